// Round 7
// baseline (727.040 us; speedup 1.0000x reference)
//
#include <hip/hip_runtime.h>
#include <hip/hip_bf16.h>

#define NN 100000
#define NE 1600000
#define NCLS 101
#define EPS_BN 1e-5f
#define NINF (-__builtin_inff())
#define NBUCK 196      // ceil(NN/512)
#define BCAP 12288     // max edges/bucket
#define G192B 521      // ceil(NN/192)
#define MBK 1563       // ceil(NN/64) mfma blocks
#define CHUNK 2048     // edges per binning block
#define KINIT 0x007Fu  // ord16(bf16 -inf)
#define NSB 3125       // ceil(NN/32) sliced-edge node blocks

typedef __attribute__((ext_vector_type(8))) short bf16x8;
typedef __attribute__((ext_vector_type(4))) float f32x4;
typedef __attribute__((ext_vector_type(2))) unsigned short u16x2;

__device__ __forceinline__ int rl_i(int v, int j) {
    return __builtin_amdgcn_readlane(v, j);
}
__device__ __forceinline__ float b2f(unsigned short u) {
    return __uint_as_float(((unsigned)u) << 16);
}
__device__ __forceinline__ unsigned short f2b(float v) {
    return __bfloat16_as_ushort(__float2bfloat16(v));
}
// order-preserving bf16 -> u16 key (max over keys == max over floats)
__device__ __forceinline__ unsigned short ord16(unsigned short b) {
    return b ^ ((b & 0x8000u) ? 0xFFFFu : 0x8000u);
}
__device__ __forceinline__ float iordf(unsigned k) {
    unsigned b = (k ^ ((k & 0x8000u) ? 0x8000u : 0xFFFFu)) & 0xFFFFu;
    return __uint_as_float(b << 16);
}
__device__ __forceinline__ u16x2 vmax2(u16x2 a, u16x2 b) {
    return __builtin_elementwise_max(a, b);
}

// ============================================================================
// CSR build, bucketed with block-level binning (unchanged).
// ============================================================================
__global__ __launch_bounds__(256) void bucket_k(const int* __restrict__ src,
                                                const int* __restrict__ dst,
                                                int* __restrict__ bcnt16,
                                                int* __restrict__ bstore) {
    __shared__ int vals[CHUNK];
    __shared__ int sval[CHUNK];
    __shared__ unsigned char bks[CHUNK];
    __shared__ unsigned char sbk[CHUNK];
    __shared__ int hist[256];
    __shared__ int scn[256];
    __shared__ int loff[256];
    __shared__ int cur[256];
    __shared__ int gshift[256];
    int e0 = blockIdx.x * CHUNK;
    int cnt = NE - e0;
    if (cnt > CHUNK) cnt = CHUNK;
    int t = threadIdx.x;
    hist[t] = 0;
    __syncthreads();
    for (int i = t; i < cnt; i += 256) {
        int d = dst[e0 + i], s = src[e0 + i];
        int b = d >> 9;
        vals[i] = ((d & 511) << 17) | s;
        bks[i] = (unsigned char)b;
        atomicAdd(&hist[b], 1);
    }
    __syncthreads();
    int v = hist[t];
    scn[t] = v;
    __syncthreads();
    for (int off = 1; off < 256; off <<= 1) {
        int u = (t >= off) ? scn[t - off] : 0;
        __syncthreads();
        scn[t] += u;
        __syncthreads();
    }
    loff[t] = scn[t] - v;
    cur[t] = scn[t] - v;
    if (t < NBUCK) {
        int base = (v > 0) ? atomicAdd(&bcnt16[t * 16], v) : 0;
        gshift[t] = base - loff[t];
    }
    __syncthreads();
    for (int i = t; i < cnt; i += 256) {
        int b = bks[i];
        int p = atomicAdd(&cur[b], 1);
        sval[p] = vals[i];
        sbk[p] = (unsigned char)b;
    }
    __syncthreads();
    for (int i = t; i < cnt; i += 256) {
        int b = sbk[i];
        int q = gshift[b] + i;
        if (q < BCAP) bstore[(size_t)b * BCAP + q] = sval[i];
    }
}

__global__ __launch_bounds__(256) void bscan_k(const int* __restrict__ bcnt16,
                                               int* __restrict__ bbase) {
    __shared__ int sh[256];
    int t = threadIdx.x;
    int v = (t < NBUCK) ? bcnt16[t * 16] : 0;
    sh[t] = v;
    __syncthreads();
    for (int off = 1; off < 256; off <<= 1) {
        int u = (t >= off) ? sh[t - off] : 0;
        __syncthreads();
        sh[t] += u;
        __syncthreads();
    }
    if (t < NBUCK) bbase[t] = sh[t] - v;
}

__global__ __launch_bounds__(512) void b2csr_k(const int* __restrict__ bcnt16,
                                               const int* __restrict__ bbase,
                                               const int* __restrict__ bstore,
                                               int* __restrict__ rs,
                                               int* __restrict__ csrc) {
    __shared__ int hist[512];
    __shared__ int scn[512];
    __shared__ int cur[512];
    int b = blockIdx.x;
    int t = threadIdx.x;
    int cnt = bcnt16[b * 16];
    if (cnt > BCAP) cnt = BCAP;
    int gbase = bbase[b];
    const int* bs = bstore + (size_t)b * BCAP;
    hist[t] = 0;
    __syncthreads();
    for (int i = t; i < cnt; i += 512) atomicAdd(&hist[bs[i] >> 17], 1);
    __syncthreads();
    int v = hist[t];
    scn[t] = v;
    __syncthreads();
    for (int off = 1; off < 512; off <<= 1) {
        int u = (t >= off) ? scn[t - off] : 0;
        __syncthreads();
        scn[t] += u;
        __syncthreads();
    }
    int ex = scn[t] - v;
    cur[t] = ex;
    int node = b * 512 + t;
    if (node < NN) rs[node] = gbase + ex;
    if (b == 0 && t == 0) rs[NN] = NE;
    __syncthreads();
    for (int i = t; i < cnt; i += 512) {
        int e = bs[i];
        int p = atomicAdd(&cur[e >> 17], 1);
        csrc[gbase + p] = e & 0x1FFFF;
    }
}

// ============================================================================
// One-shot weight packing + pos2 + wg_cls nonzero flag (folded in).
// flags[0] must be zeroed (memset) before this runs.
// ============================================================================
__global__ __launch_bounds__(256) void pack_all_k(
    const float* __restrict__ pos,
    const float* __restrict__ wl_stem, const float* __restrict__ wg_stem,
    const float* __restrict__ wl_c1, const float* __restrict__ bl_c1,
    const float* __restrict__ wl_c2, const float* __restrict__ bl_c2,
    const float* __restrict__ wg_c1, const float* __restrict__ wg_c2,
    const float* __restrict__ wl_reg, const float* __restrict__ wl_obj,
    const float* __restrict__ bl_reg, const float* __restrict__ bl_obj,
    const float* __restrict__ wl_cls, const float* __restrict__ wg_cls,
    float2* __restrict__ pos2,
    int* __restrict__ flags,
    float* __restrict__ wT_ro,
    unsigned short* __restrict__ wb_sg, unsigned short* __restrict__ wb_g1,
    unsigned short* __restrict__ wb_g2, unsigned short* __restrict__ wb_sp,
    unsigned short* __restrict__ wb_12, unsigned short* __restrict__ wb_cp,
    unsigned short* __restrict__ wcg16,
    float* __restrict__ bAB, float* __restrict__ wro, float* __restrict__ bro,
    float* __restrict__ wp_sp, float* __restrict__ wp_12,
    float* __restrict__ wp_cp, float* __restrict__ wp_ro) {
    int u = blockIdx.x * 256 + threadIdx.x;
    if (u < NN) { pos2[u] = make_float2(pos[u * 3], pos[u * 3 + 1]); return; }
    u -= NN;
    if (u < 1024) { int j = u >> 4, c = u & 15;
        wT_ro[u] = (c < 4) ? wl_reg[c * 66 + j] : ((c == 4) ? wl_obj[j] : 0.f); return; }
    u -= 1024;
    if (u < 4096) { int k = u & 63, n = (u >> 6) & 15, t2 = u >> 10;
        wb_sg[u] = f2b(wg_stem[(t2 * 16 + n) * 64 + k]); return; }
    u -= 4096;
    if (u < 4096) { int k = u & 63, n = (u >> 6) & 15, t2 = u >> 10;
        wb_g1[u] = f2b(wg_c1[(t2 * 16 + n) * 64 + k]); return; }
    u -= 4096;
    if (u < 4096) { int k = u & 63, n = (u >> 6) & 15, t2 = u >> 10;
        wb_g2[u] = f2b(wg_c2[(t2 * 16 + n) * 64 + k]); return; }
    u -= 4096;
    if (u < 4096) { int k = u & 63, n = (u >> 6) & 15, t2 = u >> 10;
        wb_sp[u] = f2b(wl_stem[(t2 * 16 + n) * 66 + k]); return; }
    u -= 4096;
    if (u < 8192) { int k = u & 63, n = (u >> 6) & 15, t2 = u >> 10;
        int cg = t2 * 16 + n;
        wb_12[u] = f2b(((cg & 1) ? wl_c2 : wl_c1)[(cg >> 1) * 66 + k]); return; }
    u -= 8192;
    if (u < 8192) { int k = u & 63, n = (u >> 6) & 15, t2 = u >> 10;
        int cg = t2 * 16 + n;
        wb_cp[u] = (cg < NCLS) ? f2b(wl_cls[cg * 66 + k]) : (unsigned short)0; return; }
    u -= 8192;
    if (u < 14336) { int k = u & 127, n = (u >> 7) & 15, t2 = u >> 11;
        int ng = t2 * 16 + n;
        float v = (ng < NCLS && k < NCLS) ? wg_cls[ng * NCLS + k] : 0.f;
        if (v != 0.f) atomicOr(&flags[0], 1);
        wcg16[u] = f2b(v); return; }
    u -= 14336;
    if (u < 128) { bAB[u] = (u & 1) ? bl_c2[u >> 1] : bl_c1[u >> 1]; return; }
    u -= 128;
    if (u < 330) { int cc = u / 66, j = u - cc * 66;
        wro[u] = (cc < 4) ? wl_reg[u] : wl_obj[j]; return; }
    u -= 330;
    if (u < 5) { bro[u] = (u < 4) ? bl_reg[u] : bl_obj[0]; return; }
    u -= 5;
    if (u < 128) { int c = u >> 1;
        wp_sp[u] = wl_stem[c * 66 + 64 + (u & 1)]; return; }
    u -= 128;
    if (u < 256) { int cg = u >> 1;
        const float* w = (cg & 1) ? wl_c2 : wl_c1;
        wp_12[u] = w[(cg >> 1) * 66 + 64 + (u & 1)]; return; }
    u -= 256;
    if (u < 256) { int cg = u >> 1;
        wp_cp[u] = (cg < NCLS) ? wl_cls[cg * 66 + 64 + (u & 1)] : 0.f; return; }
    u -= 256;
    if (u < 16) { int c = u >> 1; float v = 0.f;
        if (c < 4) v = wl_reg[c * 66 + 64 + (u & 1)];
        else if (c == 4) v = wl_obj[64 + (u & 1)];
        wp_ro[u] = v; }
}

// ============================================================================
// MFMA projection GEMM, K=64. Epilogue fuses the SOURCE pos term
// (z-transform) and stores ORDER-PRESERVING u16 keys (ord16).
// MODE 0: CHANNEL-SLICED [slice][node][8 dwords]: d = cg>>1, half = cg&1,
//         slice = d>>3  (stem: 4 slices; c1c2: 8 slices). L2-resident gathers.
// MODE 1: interleaved [n][128] (cls path, flag-gated).
// FCHK: early-exit when flags[0]==0 (cls chain dead).
// ============================================================================
template <int COUT, int NC, int IS, bool BNF, int MODE, bool FCHK>
__global__ __launch_bounds__(256) void mfma_lin_k(
    const float* __restrict__ in,
    const unsigned short* __restrict__ wb,
    const float* __restrict__ bias,
    const float* __restrict__ st,
    const float2* __restrict__ wp,
    const float2* __restrict__ pos2,
    const int* __restrict__ flags,
    unsigned short* __restrict__ out) {
    if constexpr (FCHK) { if (flags[0] == 0) return; }
    int wid = __builtin_amdgcn_readfirstlane(threadIdx.x >> 6);
    int lane = threadIdx.x & 63;
    int quad = lane >> 4, l16 = lane & 15;
    int rbase = blockIdx.x * 64 + wid * 16;
    int row = rbase + l16;
    int rcl = (row < NN) ? row : (NN - 1);
    const float* arow = in + (size_t)rcl * IS + quad * 8;
    bf16x8 a[2];
#pragma unroll
    for (int kc = 0; kc < 2; ++kc) {
        float4 v0 = *(const float4*)(arow + kc * 32);
        float4 v1 = *(const float4*)(arow + kc * 32 + 4);
        float vv[8] = {v0.x, v0.y, v0.z, v0.w, v1.x, v1.y, v1.z, v1.w};
        bf16x8 av;
#pragma unroll
        for (int j = 0; j < 8; ++j) {
            float v = vv[j];
            if constexpr (BNF) {
                int col = kc * 32 + quad * 8 + j;
                v = fmaxf(fmaf(v, st[128 + col], st[192 + col]), 0.f);
            }
            av[j] = (short)f2b(v);
        }
        a[kc] = av;
    }
    float2 pr[4];
#pragma unroll
    for (int r = 0; r < 4; ++r) {
        int rg = rbase + quad * 4 + r;
        pr[r] = pos2[(rg < NN) ? rg : 0];
    }
#pragma unroll
    for (int t = 0; t < COUT / 16; ++t) {
        const unsigned short* brow = wb + t * 1024 + l16 * 64 + quad * 8;
        f32x4 acc = {0.f, 0.f, 0.f, 0.f};
        acc = __builtin_amdgcn_mfma_f32_16x16x32_bf16(
            a[0], *(const bf16x8*)brow, acc, 0, 0, 0);
        acc = __builtin_amdgcn_mfma_f32_16x16x32_bf16(
            a[1], *(const bf16x8*)(brow + 32), acc, 0, 0, 0);
        int cg = t * 16 + l16;
        float bv = (cg < NC) ? bias[cg] : 0.f;
        float2 w = wp[cg];
#pragma unroll
        for (int r = 0; r < 4; ++r) {
            int rg = rbase + quad * 4 + r;
            if (rg < NN) {
                float val = acc[r] + bv + pr[r].x * w.x + pr[r].y * w.y;
                if constexpr (MODE == 0) {
                    int d = cg >> 1, half = cg & 1;
                    out[((size_t)(d >> 3) * NN + rg) * 16 + ((d & 7) << 1) + half] =
                        ord16(f2b(val));
                } else {
                    unsigned short hv = (cg < NC) ? ord16(f2b(val)) : (unsigned short)0;
                    out[(size_t)rg * 128 + (cg & 63) * 2 + (cg >> 6)] = hv;
                }
            }
        }
    }
}

// ============================================================================
// MFMA wg GEMM with fused BN stats. Input bf16 agg [n][64] (bit-identical).
// ============================================================================
__global__ __launch_bounds__(256) void mfma_stats_k(
    const unsigned short* __restrict__ in,   // bf16 agg [n][64]
    const unsigned short* __restrict__ wb,   // [4][16][64] bf16
    const float* __restrict__ bias,
    float* __restrict__ out,
    float* __restrict__ stpart) {
    __shared__ float sS[4][64], sQ[4][64];
    int wid = __builtin_amdgcn_readfirstlane(threadIdx.x >> 6);
    int lane = threadIdx.x & 63;
    int quad = lane >> 4, l16 = lane & 15;
    int rbase = blockIdx.x * 64 + wid * 16;
    int row = rbase + l16;
    int rcl = (row < NN) ? row : (NN - 1);
    const unsigned short* arow = in + (size_t)rcl * 64 + quad * 8;
    bf16x8 a[2];
#pragma unroll
    for (int kc = 0; kc < 2; ++kc)
        a[kc] = *(const bf16x8*)(arow + kc * 32);
#pragma unroll
    for (int t = 0; t < 4; ++t) {
        const unsigned short* brow = wb + t * 1024 + l16 * 64 + quad * 8;
        f32x4 acc = {0.f, 0.f, 0.f, 0.f};
        acc = __builtin_amdgcn_mfma_f32_16x16x32_bf16(
            a[0], *(const bf16x8*)brow, acc, 0, 0, 0);
        acc = __builtin_amdgcn_mfma_f32_16x16x32_bf16(
            a[1], *(const bf16x8*)(brow + 32), acc, 0, 0, 0);
        int cg = t * 16 + l16;
        float bv = bias[cg];
        float s = 0.f, q = 0.f;
#pragma unroll
        for (int r = 0; r < 4; ++r) {
            int rg = rbase + quad * 4 + r;
            float v = acc[r] + bv;
            if (rg < NN) out[(size_t)rg * 64 + cg] = v;
            else v = 0.f;
            s += v;
            q = fmaf(v, v, q);
        }
        s += __shfl_xor(s, 16, 64);
        s += __shfl_xor(s, 32, 64);
        q += __shfl_xor(q, 16, 64);
        q += __shfl_xor(q, 32, 64);
        if (quad == 0) {
            sS[wid][cg] = s;
            sQ[wid][cg] = q;
        }
    }
    __syncthreads();
    int c = threadIdx.x;
    if (c < 64) {
        float s = sS[0][c] + sS[1][c] + sS[2][c] + sS[3][c];
        float q = sQ[0][c] + sQ[1][c] + sQ[2][c] + sQ[3][c];
        stpart[(size_t)blockIdx.x * 128 + c] = s;
        stpart[(size_t)blockIdx.x * 128 + 64 + c] = q;
    }
}

// ============================================================================
// Vector node GEMM (tiny ro-projection head). BOUT stores ord16 keys.
// ============================================================================
template <int COUT, int CPW, int K, int IS, int OS, int MT, bool BNF, bool BOUT,
          bool POSF>
__global__ __launch_bounds__(256) void gemm_k(const float* __restrict__ in,
                                              const float* __restrict__ wT,
                                              const float* __restrict__ bias,
                                              const float* __restrict__ st,
                                              const float2* __restrict__ wp,
                                              const float2* __restrict__ pos2,
                                              float* __restrict__ out) {
    constexpr int CP = 4 * CPW;
    constexpr int RM = MT / 64;
    constexpr int XR = MT + 1;
    __shared__ __align__(16) float xs[K * XR];
    __shared__ __align__(16) float wsh[K * CP];
    int base = blockIdx.x * MT;
    for (int p = threadIdx.x; p < K * CP / 4; p += 256)
        ((float4*)wsh)[p] = ((const float4*)wT)[p];
    for (int p = threadIdx.x; p < MT * K; p += 256) {
        int n = p / K, j = p - n * K;
        float v = (base + n < NN) ? in[(size_t)(base + n) * IS + j] : 0.f;
        if constexpr (BNF) v = fmaxf(fmaf(v, st[128 + j], st[192 + j]), 0.f);
        xs[j * XR + n] = v;
    }
    __syncthreads();
    int wid = __builtin_amdgcn_readfirstlane(threadIdx.x >> 6);
    int lane = threadIdx.x & 63;
    int c0 = wid * CPW;
    if (c0 >= COUT) return;
    float acc[RM][CPW];
#pragma unroll
    for (int k = 0; k < CPW; ++k) {
        float bv = (c0 + k < COUT) ? bias[c0 + k] : 0.f;
#pragma unroll
        for (int r = 0; r < RM; ++r) acc[r][k] = bv;
    }
    for (int j = 0; j < K; ++j) {
        float a[RM];
#pragma unroll
        for (int r = 0; r < RM; ++r) a[r] = xs[j * XR + 64 * r + lane];
#pragma unroll
        for (int q = 0; q < CPW / 4; ++q) {
            float4 wv = *(const float4*)&wsh[j * CP + c0 + 4 * q];
#pragma unroll
            for (int r = 0; r < RM; ++r) {
                acc[r][4 * q + 0] = fmaf(a[r], wv.x, acc[r][4 * q + 0]);
                acc[r][4 * q + 1] = fmaf(a[r], wv.y, acc[r][4 * q + 1]);
                acc[r][4 * q + 2] = fmaf(a[r], wv.z, acc[r][4 * q + 2]);
                acc[r][4 * q + 3] = fmaf(a[r], wv.w, acc[r][4 * q + 3]);
            }
        }
    }
#pragma unroll
    for (int r = 0; r < RM; ++r) {
        int node = base + 64 * r + lane;
        if (node < NN) {
            float2 p = make_float2(0.f, 0.f);
            if constexpr (POSF) p = pos2[node];
#pragma unroll
            for (int k = 0; k < CPW; ++k) {
                if (c0 + k < COUT) {
                    float v = acc[r][k];
                    if constexpr (POSF) {
                        float2 w = wp[c0 + k];
                        v += p.x * w.x + p.y * w.y;
                    }
                    if constexpr (BOUT) {
                        unsigned short* ob = (unsigned short*)out;
                        ob[(size_t)node * OS + c0 + k] = ord16(f2b(v));
                    } else {
                        out[(size_t)node * OS + c0 + k] = v;
                    }
                }
            }
        }
    }
}

// ============================================================================
// MFMA final cls GEMM (flag-gated).
// ============================================================================
__global__ __launch_bounds__(256) void mfma_cls_k(
    const unsigned short* __restrict__ aggc16,
    const unsigned short* __restrict__ wcg16,
    const float* __restrict__ bgc,
    const int* __restrict__ flags,
    float* __restrict__ out) {
    if (flags[0] == 0) return;
    int wid = __builtin_amdgcn_readfirstlane(threadIdx.x >> 6);
    int lane = threadIdx.x & 63;
    int quad = lane >> 4;
    int l16 = lane & 15;
    int mbase = blockIdx.x * 64 + wid * 16;
    bf16x8 a[4];
    const unsigned short* arow = aggc16 + (size_t)(mbase + l16) * 128 + quad * 8;
#pragma unroll
    for (int kc = 0; kc < 4; ++kc)
        a[kc] = *(const bf16x8*)(arow + kc * 32);
    for (int t = 0; t < 7; ++t) {
        const unsigned short* brow = wcg16 + t * 2048 + l16 * 128 + quad * 8;
        f32x4 acc = {0.f, 0.f, 0.f, 0.f};
#pragma unroll
        for (int kc = 0; kc < 4; ++kc) {
            bf16x8 b = *(const bf16x8*)(brow + kc * 32);
            acc = __builtin_amdgcn_mfma_f32_16x16x32_bf16(a[kc], b, acc, 0, 0, 0);
        }
        int cg = t * 16 + l16;
        if (cg < NCLS) {
            float bv = bgc[cg];
#pragma unroll
            for (int r = 0; r < 4; ++r) {
                int rg = mbase + quad * 4 + r;
                if (rg < NN) out[(size_t)rg * NCLS + cg] = acc[r] + bv;
            }
        }
    }
}

// cls output = bias broadcast when wg_cls == 0.
__global__ __launch_bounds__(256) void fill_cls_k(const int* __restrict__ flags,
                                                  const float* __restrict__ bgc,
                                                  float* __restrict__ out) {
    if (flags[0] != 0) return;
    int idx = blockIdx.x * 256 + threadIdx.x;
    if (idx < NN * NCLS) out[idx] = bgc[idx % NCLS];
}

// reduce per-block partials -> BN scale/shift. 1024 threads, 16-way split.
__global__ __launch_bounds__(1024) void bnpar_k(const float* __restrict__ stpart,
                                                const float* __restrict__ g,
                                                const float* __restrict__ b,
                                                float* __restrict__ st, int nparts) {
    __shared__ float sS[16][64], sQ[16][64];
    int c = threadIdx.x & 63;
    int part = threadIdx.x >> 6;
    float s = 0.f, q = 0.f;
    for (int i = part; i < nparts; i += 16) {
        s += stpart[(size_t)i * 128 + c];
        q += stpart[(size_t)i * 128 + 64 + c];
    }
    sS[part][c] = s;
    sQ[part][c] = q;
    __syncthreads();
    if (part == 0) {
        s = 0.f; q = 0.f;
#pragma unroll
        for (int w = 0; w < 16; ++w) { s += sS[w][c]; q += sQ[w][c]; }
        float mu = s * (1.0f / NN);
        float var = q * (1.0f / NN) - mu * mu;
        float sc = g[c] * rsqrtf(var + EPS_BN);
        st[128 + c] = sc;
        st[192 + c] = b[c] - mu * sc;
    }
}

// ============================================================================
// CHANNEL-SLICED edge segment-max, u16 key domain. Wave = 8 nodes x 8 dword
// lanes; each lane serially maxes ITS channel-dword over its node's edge list
// (no cross-lane reduction; per-node overhead amortized over 8 nodes/wave).
// slice = blockIdx % NSL pins a 3.2MB slice to one XCD's L2 (round-robin
// dispatch). csrc re-streamed once per slice (nontemporal).
// ============================================================================
// edge1 (stem, 4 slices): dword d = channels (2d, 2d+1); out bf16 [n][64].
__global__ __launch_bounds__(256) void edge1_sl_k(
    const unsigned* __restrict__ y,          // [4][NN][8] dwords
    const float2* __restrict__ pos2,
    const int* __restrict__ rs,
    const int* __restrict__ csrc,
    const float2* __restrict__ wpsp,         // [64] per-channel pos weights
    unsigned* __restrict__ agg) {            // bf16 [n][32 dwords]
    int wid = __builtin_amdgcn_readfirstlane(threadIdx.x >> 6);
    int lane = threadIdx.x & 63;
    int slice = blockIdx.x & 3;
    int node = (blockIdx.x >> 2) * 32 + wid * 8 + (lane >> 3);
    if (node >= NN) return;
    int dw = lane & 7;
    const unsigned* ysl = y + (size_t)slice * NN * 8 + dw;
    int i0 = rs[node], i1 = rs[node + 1];
    u16x2 acc0 = {KINIT, KINIT}, acc1 = {KINIT, KINIT};
    int i = i0;
    for (; i + 4 <= i1; i += 4) {
        int s0 = __builtin_nontemporal_load(csrc + i);
        int s1 = __builtin_nontemporal_load(csrc + i + 1);
        int s2 = __builtin_nontemporal_load(csrc + i + 2);
        int s3 = __builtin_nontemporal_load(csrc + i + 3);
        u16x2 v0 = *(const u16x2*)(ysl + (size_t)s0 * 8);
        u16x2 v1 = *(const u16x2*)(ysl + (size_t)s1 * 8);
        u16x2 v2 = *(const u16x2*)(ysl + (size_t)s2 * 8);
        u16x2 v3 = *(const u16x2*)(ysl + (size_t)s3 * 8);
        acc0 = vmax2(acc0, v0);
        acc1 = vmax2(acc1, v1);
        acc0 = vmax2(acc0, v2);
        acc1 = vmax2(acc1, v3);
    }
    for (; i < i1; ++i) {
        int s = __builtin_nontemporal_load(csrc + i);
        acc0 = vmax2(acc0, *(const u16x2*)(ysl + (size_t)s * 8));
    }
    u16x2 acc = vmax2(acc0, acc1);
    float2 pd = pos2[node];
    int d = slice * 8 + dw;
    float2 w0 = wpsp[2 * d], w1 = wpsp[2 * d + 1];
    float v0 = fmaxf(iordf(acc.x) - fmaf(pd.y, w0.y, pd.x * w0.x), 0.f);
    float v1 = fmaxf(iordf(acc.y) - fmaf(pd.y, w1.y, pd.x * w1.x), 0.f);
    agg[(size_t)node * 32 + d] = (unsigned)f2b(v0) | ((unsigned)f2b(v1) << 16);
}

// edge2 (c1/c2 pairs, 8 slices): dword d = (c1_d, c2_d); out bf16 a1/a2 [n][64].
__global__ __launch_bounds__(256) void edge2_sl_k(
    const unsigned* __restrict__ y,          // [8][NN][8] dwords
    const float2* __restrict__ pos2,
    const int* __restrict__ rs,
    const int* __restrict__ csrc,
    const float2* __restrict__ wp12,         // [128] interleaved c1/c2
    unsigned short* __restrict__ a1,         // bf16 [n][64]
    unsigned short* __restrict__ a2) {
    int wid = __builtin_amdgcn_readfirstlane(threadIdx.x >> 6);
    int lane = threadIdx.x & 63;
    int slice = blockIdx.x & 7;
    int node = (blockIdx.x >> 3) * 32 + wid * 8 + (lane >> 3);
    if (node >= NN) return;
    int dw = lane & 7;
    const unsigned* ysl = y + (size_t)slice * NN * 8 + dw;
    int i0 = rs[node], i1 = rs[node + 1];
    u16x2 acc0 = {KINIT, KINIT}, acc1 = {KINIT, KINIT};
    int i = i0;
    for (; i + 4 <= i1; i += 4) {
        int s0 = __builtin_nontemporal_load(csrc + i);
        int s1 = __builtin_nontemporal_load(csrc + i + 1);
        int s2 = __builtin_nontemporal_load(csrc + i + 2);
        int s3 = __builtin_nontemporal_load(csrc + i + 3);
        u16x2 v0 = *(const u16x2*)(ysl + (size_t)s0 * 8);
        u16x2 v1 = *(const u16x2*)(ysl + (size_t)s1 * 8);
        u16x2 v2 = *(const u16x2*)(ysl + (size_t)s2 * 8);
        u16x2 v3 = *(const u16x2*)(ysl + (size_t)s3 * 8);
        acc0 = vmax2(acc0, v0);
        acc1 = vmax2(acc1, v1);
        acc0 = vmax2(acc0, v2);
        acc1 = vmax2(acc1, v3);
    }
    for (; i < i1; ++i) {
        int s = __builtin_nontemporal_load(csrc + i);
        acc0 = vmax2(acc0, *(const u16x2*)(ysl + (size_t)s * 8));
    }
    u16x2 acc = vmax2(acc0, acc1);
    float2 pd = pos2[node];
    int d = slice * 8 + dw;
    float2 wA = wp12[2 * d], wB = wp12[2 * d + 1];
    a1[(size_t)node * 64 + d] =
        f2b(fmaxf(iordf(acc.x) - fmaf(pd.y, wA.y, pd.x * wA.x), 0.0f));
    a2[(size_t)node * 64 + d] =
        f2b(fmaxf(iordf(acc.y) - fmaf(pd.y, wB.y, pd.x * wB.x), 0.0f));
}

// cls edge pass (flag-gated), key domain, interleaved dword gathers (R2
// layout — dead in this problem unless wg_cls != 0).
__global__ __launch_bounds__(256) void edge_cls_k(
    const unsigned* __restrict__ y32,        // interleaved cls keys, stride 64
    const float2* __restrict__ pos2,
    const int* __restrict__ rs,
    const int* __restrict__ csrc,
    const float* __restrict__ wl,            // (101,66)
    const int* __restrict__ flags,
    unsigned short* __restrict__ aggb) {
    if (flags[0] == 0) return;
    int wid = __builtin_amdgcn_readfirstlane(threadIdx.x >> 6);
    int lane = threadIdx.x & 63;
    int node = blockIdx.x * 4 + wid;
    if (node >= NN) return;
    int chi = (lane + 64 < NCLS) ? (lane + 64) : (NCLS - 1);
    float wa0 = wl[lane * 66 + 64], wa1 = wl[lane * 66 + 65];
    float wb0 = wl[chi * 66 + 64], wb1 = wl[chi * 66 + 65];
    float2 pd = pos2[node];
    int i0 = rs[node], i1 = rs[node + 1];
    u16x2 acc0 = {KINIT, KINIT}, acc1 = {KINIT, KINIT};
    for (int ib = i0; ib < i1; ib += 64) {
        int m = i1 - ib;
        if (m > 64) m = 64;
        int t = ib + lane;
        int idx = (t < i1) ? csrc[t] : 0;
        int j = 0;
        for (; j + 8 <= m; j += 8) {
            u16x2 w[8];
#pragma unroll
            for (int q = 0; q < 8; ++q)
                w[q] = *(const u16x2*)(y32 + (size_t)rl_i(idx, j + q) * 64 + lane);
#pragma unroll
            for (int q = 0; q < 8; q += 2) {
                acc0 = vmax2(acc0, w[q]);
                acc1 = vmax2(acc1, w[q + 1]);
            }
        }
        for (; j < m; ++j)
            acc0 = vmax2(acc0,
                *(const u16x2*)(y32 + (size_t)rl_i(idx, j) * 64 + lane));
    }
    u16x2 acc = vmax2(acc0, acc1);
    aggb[(size_t)node * 128 + lane] =
        f2b(fmaxf(iordf(acc.x) - fmaf(pd.y, wa1, pd.x * wa0), 0.0f));
    unsigned short hb = (lane + 64 < NCLS)
        ? f2b(fmaxf(iordf(acc.y) - fmaf(pd.y, wb1, pd.x * wb0), 0.0f))
        : (unsigned short)0;
    aggb[(size_t)node * 128 + 64 + lane] = hb;
}

// reg/obj edge pass: wave per node; 8 edge-slots x 8 channel-slots.
// (yro table = 1.6 MB — L2-resident per XCD without slicing.)
__global__ __launch_bounds__(256) void edge_ro_k(
    const unsigned short* __restrict__ yro,  // keys, stride 8
    const float2* __restrict__ pos2,
    const int* __restrict__ rs,
    const int* __restrict__ csrc,
    const float2* __restrict__ wpro,         // [8]
    float* __restrict__ aggr,
    float* __restrict__ aggo) {
    int wid = __builtin_amdgcn_readfirstlane(threadIdx.x >> 6);
    int lane = threadIdx.x & 63;
    int node = blockIdx.x * 4 + wid;
    if (node >= NN) return;
    int k = lane >> 3, c = lane & 7;
    int cc = (c < 5) ? c : 4;
    float2 wv = wpro[cc];
    int i0 = rs[node], i1 = rs[node + 1];
    unsigned ka = KINIT;
    for (int i = i0 + k; i < i1; i += 8) {
        int s = csrc[i];
        unsigned kv = yro[(size_t)s * 8 + cc];
        ka = (kv > ka) ? kv : ka;
    }
    unsigned o;
    o = (unsigned)__shfl_xor((int)ka, 8, 64);  ka = (o > ka) ? o : ka;
    o = (unsigned)__shfl_xor((int)ka, 16, 64); ka = (o > ka) ? o : ka;
    o = (unsigned)__shfl_xor((int)ka, 32, 64); ka = (o > ka) ? o : ka;
    float2 pd = pos2[node];
    float acc_f = fmaxf(iordf(ka) - fmaf(pd.y, wv.y, pd.x * wv.x), 0.0f);
    if (lane < 5) {
        if (lane < 4) aggr[(size_t)node * 4 + lane] = acc_f;
        else          aggo[node] = acc_f;
    }
}

__global__ __launch_bounds__(256) void final_ro_k(const float* __restrict__ aggr,
                                                  const float* __restrict__ aggo,
                                                  const float* __restrict__ wgr,
                                                  const float* __restrict__ bgr,
                                                  const float* __restrict__ wgo,
                                                  const float* __restrict__ bgo,
                                                  float* __restrict__ out) {
    int n = blockIdx.x * 256 + threadIdx.x;
    if (n >= NN) return;
    float a0 = aggr[(size_t)n * 4 + 0], a1 = aggr[(size_t)n * 4 + 1];
    float a2 = aggr[(size_t)n * 4 + 2], a3 = aggr[(size_t)n * 4 + 3];
    float* reg = out + (size_t)NN * NCLS;
    float* obj = reg + (size_t)NN * 4;
#pragma unroll
    for (int k = 0; k < 4; ++k) {
        float acc = bgr[k];
        acc = fmaf(a0, wgr[k * 4 + 0], acc);
        acc = fmaf(a1, wgr[k * 4 + 1], acc);
        acc = fmaf(a2, wgr[k * 4 + 2], acc);
        acc = fmaf(a3, wgr[k * 4 + 3], acc);
        reg[(size_t)n * 4 + k] = acc;
    }
    obj[n] = fmaf(aggo[n], wgo[0], bgo[0]);
}

// ============================================================================
extern "C" void kernel_launch(void* const* d_in, const int* in_sizes, int n_in,
                              void* d_out, int out_size, void* d_ws, size_t ws_size,
                              hipStream_t stream) {
    const float* x   = (const float*)d_in[0];
    const float* pos = (const float*)d_in[1];
    const int* ei    = (const int*)d_in[2];
    const int* src = ei;
    const int* dst = ei + NE;
    const float* wl_stem = (const float*)d_in[3];
    const float* bl_stem = (const float*)d_in[4];
    const float* wg_stem = (const float*)d_in[5];
    const float* bg_stem = (const float*)d_in[6];
    const float* g_stem  = (const float*)d_in[7];
    const float* b_stem  = (const float*)d_in[8];
    const float* wl_c1 = (const float*)d_in[9];
    const float* bl_c1 = (const float*)d_in[10];
    const float* wg_c1 = (const float*)d_in[11];
    const float* bg_c1 = (const float*)d_in[12];
    const float* g_c1  = (const float*)d_in[13];
    const float* b_c1  = (const float*)d_in[14];
    const float* wl_c2 = (const float*)d_in[15];
    const float* bl_c2 = (const float*)d_in[16];
    const float* wg_c2 = (const float*)d_in[17];
    const float* bg_c2 = (const float*)d_in[18];
    const float* g_c2  = (const float*)d_in[19];
    const float* b_c2  = (const float*)d_in[20];
    const float* wl_reg = (const float*)d_in[21];
    const float* bl_reg = (const float*)d_in[22];
    const float* wg_reg = (const float*)d_in[23];
    const float* bg_reg = (const float*)d_in[24];
    const float* wl_cls = (const float*)d_in[25];
    const float* bl_cls = (const float*)d_in[26];
    const float* wg_cls = (const float*)d_in[27];
    const float* bg_cls = (const float*)d_in[28];
    const float* wl_obj = (const float*)d_in[29];
    const float* bl_obj = (const float*)d_in[30];
    const float* wg_obj = (const float*)d_in[31];
    const float* bg_obj = (const float*)d_in[32];

    float* ws = (float*)d_ws;
    // Arena: S0[N*128] | S1[N*64] | S2[N*64] | S3[N*64] | ints/smalls
    float* S0 = ws;
    float* S1 = S0 + (size_t)NN * 128;
    float* S2 = S1 + (size_t)NN * 64;
    float* S3 = S2 + (size_t)NN * 64;
    float* y12   = S0;       // sliced keys [8][n][8dw] (first half of S0)
    float* y_cls = S0;       // interleaved keys [n][128]
    // bf16 agg buffers in S0's second half (free during conv phases)
    unsigned short* B0 = (unsigned short*)(S0 + (size_t)NN * 64);  // [n][64] bf16
    unsigned short* B1 = B0 + (size_t)NN * 64;                     // [n][64] bf16
    unsigned short* aggc16 = (unsigned short*)S1;   // bf16 [n][128]
    int*   bstore = (int*)S0;                     // NBUCK*BCAP ints (CSR phase)
    int*   rs   = (int*)(S3 + (size_t)NN * 64);   // NN+1 (padded)
    int*   csrc = rs + 100016;                    // NE
    float* pos2 = (float*)(csrc + NE);            // NN float2
    float* y_ro = pos2 + (size_t)NN * 2;          // key [n][8] (fp32-sized slot)
    float* aggr = y_ro + (size_t)NN * 8;          // NN*4
    float* aggo = aggr + (size_t)NN * 4;          // NN
    float* st   = aggo + NN;                      // 3*256 (params at [128..255])
    float* st0 = st, *st1 = st + 256, *st2 = st + 512;
    float* wro = st + 768;                        // 336
    float* bro = wro + 336;                       // 16
    int*   bcnt16 = (int*)(bro + 16);             // NBUCK*16
    int*   flags  = bcnt16 + NBUCK * 16;          // 16 ints (zeroed with bcnt16)
    int*   bbase  = flags + 16;                   // 256
    float* wT_ro = (float*)(bbase + 256);         // [64][16] fp32
    unsigned short* wb_sg = (unsigned short*)(wT_ro + 1024);  // 4096
    unsigned short* wb_g1 = wb_sg + 4096;                     // 4096
    unsigned short* wb_g2 = wb_g1 + 4096;                     // 4096
    unsigned short* wb_sp = wb_g2 + 4096;                     // 4096
    unsigned short* wb_12 = wb_sp + 4096;                     // 8192
    unsigned short* wb_cp = wb_12 + 8192;                     // 8192
    unsigned short* wcg16 = wb_cp + 8192;                     // 14336
    float* bAB   = (float*)(wcg16 + 14336);       // 128
    float* wp_sp = bAB + 128;                     // 128 (64 float2)
    float* wp_12 = wp_sp + 128;                   // 256 (128 float2)
    float* wp_cp = wp_12 + 256;                   // 256 (128 float2)
    float* wp_ro = wp_cp + 256;                   // 16  (8 float2)
    float* stpart = wp_ro + 16;                   // MBK*128 floats (~800 KB)

    hipMemsetAsync(bcnt16, 0, (NBUCK * 16 + 16) * sizeof(int), stream);

    const int NB = (NN + 255) / 256;      // 391
    const int N4 = (NN + 3) / 4;          // 25000
    const int CB = (NE + CHUNK - 1) / CHUNK;  // 782
    const int PB = (NN + 49157 + 255) / 256;  // pack_all grid (pos2 folded in)

    // ---- packing (+pos2+flag) + CSR build ----
    pack_all_k<<<PB, 256, 0, stream>>>(pos,
                                       wl_stem, wg_stem, wl_c1, bl_c1, wl_c2,
                                       bl_c2, wg_c1, wg_c2, wl_reg, wl_obj,
                                       bl_reg, bl_obj, wl_cls, wg_cls,
                                       (float2*)pos2, flags,
                                       wT_ro, wb_sg, wb_g1, wb_g2, wb_sp,
                                       wb_12, wb_cp, wcg16, bAB, wro, bro,
                                       wp_sp, wp_12, wp_cp, wp_ro);
    bucket_k<<<CB, 256, 0, stream>>>(src, dst, bcnt16, bstore);
    bscan_k<<<1, 256, 0, stream>>>(bcnt16, bbase);
    b2csr_k<<<NBUCK, 512, 0, stream>>>(bcnt16, bbase, bstore, rs, csrc);

    // ---- stem (sliced keys: 4 slices in S1) ----
    mfma_lin_k<64, 64, 64, false, 0, false><<<MBK, 256, 0, stream>>>(
        x, wb_sp, bl_stem, nullptr, (const float2*)wp_sp, (const float2*)pos2,
        flags, (unsigned short*)S1);
    edge1_sl_k<<<4 * NSB, 256, 0, stream>>>((const unsigned*)S1,
                                            (float2*)pos2, rs, csrc,
                                            (const float2*)wp_sp,
                                            (unsigned*)B0);  // bf16 agg
    mfma_stats_k<<<MBK, 256, 0, stream>>>(B0, wb_sg, bg_stem, S2, stpart);
    bnpar_k<<<1, 1024, 0, stream>>>(stpart, g_stem, b_stem, st0, MBK);

    // ---- c1 + c2 (sliced keys: 8 slices in S0; shared sliced edge pass) ----
    mfma_lin_k<128, 128, 64, true, 0, false><<<MBK, 256, 0, stream>>>(
        S2, wb_12, bAB, st0, (const float2*)wp_12, (const float2*)pos2,
        flags, (unsigned short*)y12);
    edge2_sl_k<<<8 * NSB, 256, 0, stream>>>((const unsigned*)y12,
                                            (float2*)pos2, rs, csrc,
                                            (const float2*)wp_12, B0, B1);
    mfma_stats_k<<<MBK, 256, 0, stream>>>(B0, wb_g1, bg_c1, S1, stpart);
    bnpar_k<<<1, 1024, 0, stream>>>(stpart, g_c1, b_c1, st1, MBK);
    mfma_stats_k<<<MBK, 256, 0, stream>>>(B1, wb_g2, bg_c2, S3, stpart);
    bnpar_k<<<1, 1024, 0, stream>>>(stpart, g_c2, b_c2, st2, MBK);

    // ---- reg + obj projection (input x1 = BN(S1), fused; keys out) ----
    gemm_k<5, 4, 64, 64, 8, 192, true, true, true><<<G192B, 256, 0, stream>>>(
        S1, wT_ro, bro, st1, (const float2*)wp_ro, (const float2*)pos2, y_ro);
    // ---- cls projection (flag-gated; interleaved key pairs) ----
    mfma_lin_k<128, NCLS, 64, true, 1, true><<<MBK, 256, 0, stream>>>(
        S3, wb_cp, bl_cls, st2, (const float2*)wp_cp, (const float2*)pos2,
        flags, (unsigned short*)y_cls);

    // ---- cls edge pass (flag-gated) + reg/obj edge pass ----
    edge_cls_k<<<N4, 256, 0, stream>>>((const unsigned*)y_cls, (float2*)pos2,
                                       rs, csrc, wl_cls, flags, aggc16);
    edge_ro_k<<<N4, 256, 0, stream>>>((const unsigned short*)y_ro,
                                      (float2*)pos2, rs, csrc,
                                      (const float2*)wp_ro, aggr, aggo);

    mfma_cls_k<<<MBK, 256, 0, stream>>>(aggc16, wcg16, bg_cls, flags,
                                        (float*)d_out);
    fill_cls_k<<<(NN * NCLS + 255) / 256, 256, 0, stream>>>(flags, bg_cls,
                                                            (float*)d_out);
    final_ro_k<<<NB, 256, 0, stream>>>(aggr, aggo, wg_reg, bg_reg, wg_obj, bg_obj,
                                       (float*)d_out);
}

// Round 8
// 460.433 us; speedup vs baseline: 1.5790x; 1.5790x over previous
//
#include <hip/hip_runtime.h>
#include <hip/hip_bf16.h>

#define NN 100000
#define NE 1600000
#define NCLS 101
#define EPS_BN 1e-5f
#define NINF (-__builtin_inff())
#define NBUCK 196      // ceil(NN/512)
#define BCAP 12288     // max edges/bucket
#define G192B 521      // ceil(NN/192)
#define MBK 1563       // ceil(NN/64) mfma blocks
#define CHUNK 2048     // edges per binning block
#define KINIT 0x007Fu  // ord16(bf16 -inf)

typedef __attribute__((ext_vector_type(8))) short bf16x8;
typedef __attribute__((ext_vector_type(4))) float f32x4;
typedef __attribute__((ext_vector_type(2))) unsigned short u16x2;

__device__ __forceinline__ int rl_i(int v, int j) {
    return __builtin_amdgcn_readlane(v, j);
}
__device__ __forceinline__ int bperm(int srcbyte, int v) {
    return __builtin_amdgcn_ds_bpermute(srcbyte, v);
}
__device__ __forceinline__ float b2f(unsigned short u) {
    return __uint_as_float(((unsigned)u) << 16);
}
__device__ __forceinline__ unsigned short f2b(float v) {
    return __bfloat16_as_ushort(__float2bfloat16(v));
}
// order-preserving bf16 -> u16 key (max over keys == max over floats)
__device__ __forceinline__ unsigned short ord16(unsigned short b) {
    return b ^ ((b & 0x8000u) ? 0xFFFFu : 0x8000u);
}
__device__ __forceinline__ float iordf(unsigned k) {
    unsigned b = (k ^ ((k & 0x8000u) ? 0x8000u : 0xFFFFu)) & 0xFFFFu;
    return __uint_as_float(b << 16);
}
__device__ __forceinline__ u16x2 vmax2(u16x2 a, u16x2 b) {
    return __builtin_elementwise_max(a, b);
}

// ============================================================================
// CSR build, bucketed with block-level binning (unchanged).
// ============================================================================
__global__ __launch_bounds__(256) void bucket_k(const int* __restrict__ src,
                                                const int* __restrict__ dst,
                                                int* __restrict__ bcnt16,
                                                int* __restrict__ bstore) {
    __shared__ int vals[CHUNK];
    __shared__ int sval[CHUNK];
    __shared__ unsigned char bks[CHUNK];
    __shared__ unsigned char sbk[CHUNK];
    __shared__ int hist[256];
    __shared__ int scn[256];
    __shared__ int loff[256];
    __shared__ int cur[256];
    __shared__ int gshift[256];
    int e0 = blockIdx.x * CHUNK;
    int cnt = NE - e0;
    if (cnt > CHUNK) cnt = CHUNK;
    int t = threadIdx.x;
    hist[t] = 0;
    __syncthreads();
    for (int i = t; i < cnt; i += 256) {
        int d = dst[e0 + i], s = src[e0 + i];
        int b = d >> 9;
        vals[i] = ((d & 511) << 17) | s;
        bks[i] = (unsigned char)b;
        atomicAdd(&hist[b], 1);
    }
    __syncthreads();
    int v = hist[t];
    scn[t] = v;
    __syncthreads();
    for (int off = 1; off < 256; off <<= 1) {
        int u = (t >= off) ? scn[t - off] : 0;
        __syncthreads();
        scn[t] += u;
        __syncthreads();
    }
    loff[t] = scn[t] - v;
    cur[t] = scn[t] - v;
    if (t < NBUCK) {
        int base = (v > 0) ? atomicAdd(&bcnt16[t * 16], v) : 0;
        gshift[t] = base - loff[t];
    }
    __syncthreads();
    for (int i = t; i < cnt; i += 256) {
        int b = bks[i];
        int p = atomicAdd(&cur[b], 1);
        sval[p] = vals[i];
        sbk[p] = (unsigned char)b;
    }
    __syncthreads();
    for (int i = t; i < cnt; i += 256) {
        int b = sbk[i];
        int q = gshift[b] + i;
        if (q < BCAP) bstore[(size_t)b * BCAP + q] = sval[i];
    }
}

__global__ __launch_bounds__(256) void bscan_k(const int* __restrict__ bcnt16,
                                               int* __restrict__ bbase) {
    __shared__ int sh[256];
    int t = threadIdx.x;
    int v = (t < NBUCK) ? bcnt16[t * 16] : 0;
    sh[t] = v;
    __syncthreads();
    for (int off = 1; off < 256; off <<= 1) {
        int u = (t >= off) ? sh[t - off] : 0;
        __syncthreads();
        sh[t] += u;
        __syncthreads();
    }
    if (t < NBUCK) bbase[t] = sh[t] - v;
}

__global__ __launch_bounds__(512) void b2csr_k(const int* __restrict__ bcnt16,
                                               const int* __restrict__ bbase,
                                               const int* __restrict__ bstore,
                                               int* __restrict__ rs,
                                               int* __restrict__ csrc) {
    __shared__ int hist[512];
    __shared__ int scn[512];
    __shared__ int cur[512];
    int b = blockIdx.x;
    int t = threadIdx.x;
    int cnt = bcnt16[b * 16];
    if (cnt > BCAP) cnt = BCAP;
    int gbase = bbase[b];
    const int* bs = bstore + (size_t)b * BCAP;
    hist[t] = 0;
    __syncthreads();
    for (int i = t; i < cnt; i += 512) atomicAdd(&hist[bs[i] >> 17], 1);
    __syncthreads();
    int v = hist[t];
    scn[t] = v;
    __syncthreads();
    for (int off = 1; off < 512; off <<= 1) {
        int u = (t >= off) ? scn[t - off] : 0;
        __syncthreads();
        scn[t] += u;
        __syncthreads();
    }
    int ex = scn[t] - v;
    cur[t] = ex;
    int node = b * 512 + t;
    if (node < NN) rs[node] = gbase + ex;
    if (b == 0 && t == 0) rs[NN] = NE;
    __syncthreads();
    for (int i = t; i < cnt; i += 512) {
        int e = bs[i];
        int p = atomicAdd(&cur[e >> 17], 1);
        csrc[gbase + p] = e & 0x1FFFF;
    }
}

// ============================================================================
// One-shot weight packing + pos2 + wg_cls nonzero flag (folded in).
// flags[0] must be zeroed (memset) before this runs.
// ============================================================================
__global__ __launch_bounds__(256) void pack_all_k(
    const float* __restrict__ pos,
    const float* __restrict__ wl_stem, const float* __restrict__ wg_stem,
    const float* __restrict__ wl_c1, const float* __restrict__ bl_c1,
    const float* __restrict__ wl_c2, const float* __restrict__ bl_c2,
    const float* __restrict__ wg_c1, const float* __restrict__ wg_c2,
    const float* __restrict__ wl_reg, const float* __restrict__ wl_obj,
    const float* __restrict__ bl_reg, const float* __restrict__ bl_obj,
    const float* __restrict__ wl_cls, const float* __restrict__ wg_cls,
    float2* __restrict__ pos2,
    int* __restrict__ flags,
    float* __restrict__ wT_ro,
    unsigned short* __restrict__ wb_sg, unsigned short* __restrict__ wb_g1,
    unsigned short* __restrict__ wb_g2, unsigned short* __restrict__ wb_sp,
    unsigned short* __restrict__ wb_12, unsigned short* __restrict__ wb_cp,
    unsigned short* __restrict__ wcg16,
    float* __restrict__ bAB, float* __restrict__ wro, float* __restrict__ bro,
    float* __restrict__ wp_sp, float* __restrict__ wp_12,
    float* __restrict__ wp_cp, float* __restrict__ wp_ro) {
    int u = blockIdx.x * 256 + threadIdx.x;
    if (u < NN) { pos2[u] = make_float2(pos[u * 3], pos[u * 3 + 1]); return; }
    u -= NN;
    if (u < 1024) { int j = u >> 4, c = u & 15;
        wT_ro[u] = (c < 4) ? wl_reg[c * 66 + j] : ((c == 4) ? wl_obj[j] : 0.f); return; }
    u -= 1024;
    if (u < 4096) { int k = u & 63, n = (u >> 6) & 15, t2 = u >> 10;
        wb_sg[u] = f2b(wg_stem[(t2 * 16 + n) * 64 + k]); return; }
    u -= 4096;
    if (u < 4096) { int k = u & 63, n = (u >> 6) & 15, t2 = u >> 10;
        wb_g1[u] = f2b(wg_c1[(t2 * 16 + n) * 64 + k]); return; }
    u -= 4096;
    if (u < 4096) { int k = u & 63, n = (u >> 6) & 15, t2 = u >> 10;
        wb_g2[u] = f2b(wg_c2[(t2 * 16 + n) * 64 + k]); return; }
    u -= 4096;
    if (u < 4096) { int k = u & 63, n = (u >> 6) & 15, t2 = u >> 10;
        wb_sp[u] = f2b(wl_stem[(t2 * 16 + n) * 66 + k]); return; }
    u -= 4096;
    if (u < 8192) { int k = u & 63, n = (u >> 6) & 15, t2 = u >> 10;
        int cg = t2 * 16 + n;
        wb_12[u] = f2b(((cg & 1) ? wl_c2 : wl_c1)[(cg >> 1) * 66 + k]); return; }
    u -= 8192;
    if (u < 8192) { int k = u & 63, n = (u >> 6) & 15, t2 = u >> 10;
        int cg = t2 * 16 + n;
        wb_cp[u] = (cg < NCLS) ? f2b(wl_cls[cg * 66 + k]) : (unsigned short)0; return; }
    u -= 8192;
    if (u < 14336) { int k = u & 127, n = (u >> 7) & 15, t2 = u >> 11;
        int ng = t2 * 16 + n;
        float v = (ng < NCLS && k < NCLS) ? wg_cls[ng * NCLS + k] : 0.f;
        if (v != 0.f) atomicOr(&flags[0], 1);
        wcg16[u] = f2b(v); return; }
    u -= 14336;
    if (u < 128) { bAB[u] = (u & 1) ? bl_c2[u >> 1] : bl_c1[u >> 1]; return; }
    u -= 128;
    if (u < 330) { int cc = u / 66, j = u - cc * 66;
        wro[u] = (cc < 4) ? wl_reg[u] : wl_obj[j]; return; }
    u -= 330;
    if (u < 5) { bro[u] = (u < 4) ? bl_reg[u] : bl_obj[0]; return; }
    u -= 5;
    if (u < 128) { int c = u >> 1;
        wp_sp[u] = wl_stem[c * 66 + 64 + (u & 1)]; return; }
    u -= 128;
    if (u < 256) { int cg = u >> 1;
        const float* w = (cg & 1) ? wl_c2 : wl_c1;
        wp_12[u] = w[(cg >> 1) * 66 + 64 + (u & 1)]; return; }
    u -= 256;
    if (u < 256) { int cg = u >> 1;
        wp_cp[u] = (cg < NCLS) ? wl_cls[cg * 66 + 64 + (u & 1)] : 0.f; return; }
    u -= 256;
    if (u < 16) { int c = u >> 1; float v = 0.f;
        if (c < 4) v = wl_reg[c * 66 + 64 + (u & 1)];
        else if (c == 4) v = wl_obj[64 + (u & 1)];
        wp_ro[u] = v; }
}

// ============================================================================
// MFMA projection GEMM, K=64. Epilogue fuses the SOURCE pos term
// (z-transform) and stores ORDER-PRESERVING u16 keys (ord16).
// FCHK: early-exit when flags[0]==0 (cls chain dead).
// ============================================================================
template <int COUT, int NC, int IS, int OS, bool BNF, bool ILV, bool FCHK>
__global__ __launch_bounds__(256) void mfma_lin_k(
    const float* __restrict__ in,
    const unsigned short* __restrict__ wb,
    const float* __restrict__ bias,
    const float* __restrict__ st,
    const float2* __restrict__ wp,
    const float2* __restrict__ pos2,
    const int* __restrict__ flags,
    unsigned short* __restrict__ out) {
    if constexpr (FCHK) { if (flags[0] == 0) return; }
    int wid = __builtin_amdgcn_readfirstlane(threadIdx.x >> 6);
    int lane = threadIdx.x & 63;
    int quad = lane >> 4, l16 = lane & 15;
    int rbase = blockIdx.x * 64 + wid * 16;
    int row = rbase + l16;
    int rcl = (row < NN) ? row : (NN - 1);
    const float* arow = in + (size_t)rcl * IS + quad * 8;
    bf16x8 a[2];
#pragma unroll
    for (int kc = 0; kc < 2; ++kc) {
        float4 v0 = *(const float4*)(arow + kc * 32);
        float4 v1 = *(const float4*)(arow + kc * 32 + 4);
        float vv[8] = {v0.x, v0.y, v0.z, v0.w, v1.x, v1.y, v1.z, v1.w};
        bf16x8 av;
#pragma unroll
        for (int j = 0; j < 8; ++j) {
            float v = vv[j];
            if constexpr (BNF) {
                int col = kc * 32 + quad * 8 + j;
                v = fmaxf(fmaf(v, st[128 + col], st[192 + col]), 0.f);
            }
            av[j] = (short)f2b(v);
        }
        a[kc] = av;
    }
    float2 pr[4];
#pragma unroll
    for (int r = 0; r < 4; ++r) {
        int rg = rbase + quad * 4 + r;
        pr[r] = pos2[(rg < NN) ? rg : 0];
    }
#pragma unroll
    for (int t = 0; t < COUT / 16; ++t) {
        const unsigned short* brow = wb + t * 1024 + l16 * 64 + quad * 8;
        f32x4 acc = {0.f, 0.f, 0.f, 0.f};
        acc = __builtin_amdgcn_mfma_f32_16x16x32_bf16(
            a[0], *(const bf16x8*)brow, acc, 0, 0, 0);
        acc = __builtin_amdgcn_mfma_f32_16x16x32_bf16(
            a[1], *(const bf16x8*)(brow + 32), acc, 0, 0, 0);
        int cg = t * 16 + l16;
        float bv = (cg < NC) ? bias[cg] : 0.f;
        float2 w = wp[cg];
#pragma unroll
        for (int r = 0; r < 4; ++r) {
            int rg = rbase + quad * 4 + r;
            if (rg < NN) {
                float val = acc[r] + bv + pr[r].x * w.x + pr[r].y * w.y;
                if constexpr (ILV) {
                    unsigned short hv = (cg < NC) ? ord16(f2b(val)) : (unsigned short)0;
                    out[(size_t)rg * OS + (cg & 63) * 2 + (cg >> 6)] = hv;
                } else {
                    if (cg < NC) out[(size_t)rg * OS + cg] = ord16(f2b(val));
                }
            }
        }
    }
}

// ============================================================================
// MFMA wg GEMM with fused BN stats. Input bf16 agg [n][64] (bit-identical —
// fp32 agg precision was never used). Per-block column (s,q) partials are
// ATOMICALLY accumulated into an 8-copy global accumulator acc[8][128]
// (replaces the 800 KB stpart array + single-block bnpar scan).
// ============================================================================
__global__ __launch_bounds__(256) void mfma_stats_k(
    const unsigned short* __restrict__ in,   // bf16 agg [n][64]
    const unsigned short* __restrict__ wb,   // [4][16][64] bf16
    const float* __restrict__ bias,
    float* __restrict__ out,
    float* __restrict__ acc8) {              // [8][128] zeroed accumulator
    __shared__ float sS[4][64], sQ[4][64];
    int wid = __builtin_amdgcn_readfirstlane(threadIdx.x >> 6);
    int lane = threadIdx.x & 63;
    int quad = lane >> 4, l16 = lane & 15;
    int rbase = blockIdx.x * 64 + wid * 16;
    int row = rbase + l16;
    int rcl = (row < NN) ? row : (NN - 1);
    const unsigned short* arow = in + (size_t)rcl * 64 + quad * 8;
    bf16x8 a[2];
#pragma unroll
    for (int kc = 0; kc < 2; ++kc)
        a[kc] = *(const bf16x8*)(arow + kc * 32);
#pragma unroll
    for (int t = 0; t < 4; ++t) {
        const unsigned short* brow = wb + t * 1024 + l16 * 64 + quad * 8;
        f32x4 acc = {0.f, 0.f, 0.f, 0.f};
        acc = __builtin_amdgcn_mfma_f32_16x16x32_bf16(
            a[0], *(const bf16x8*)brow, acc, 0, 0, 0);
        acc = __builtin_amdgcn_mfma_f32_16x16x32_bf16(
            a[1], *(const bf16x8*)(brow + 32), acc, 0, 0, 0);
        int cg = t * 16 + l16;
        float bv = bias[cg];
        float s = 0.f, q = 0.f;
#pragma unroll
        for (int r = 0; r < 4; ++r) {
            int rg = rbase + quad * 4 + r;
            float v = acc[r] + bv;
            if (rg < NN) out[(size_t)rg * 64 + cg] = v;
            else v = 0.f;
            s += v;
            q = fmaf(v, v, q);
        }
        s += __shfl_xor(s, 16, 64);
        s += __shfl_xor(s, 32, 64);
        q += __shfl_xor(q, 16, 64);
        q += __shfl_xor(q, 32, 64);
        if (quad == 0) {
            sS[wid][cg] = s;
            sQ[wid][cg] = q;
        }
    }
    __syncthreads();
    int c = threadIdx.x;
    if (c < 64) {
        float s = sS[0][c] + sS[1][c] + sS[2][c] + sS[3][c];
        float q = sQ[0][c] + sQ[1][c] + sQ[2][c] + sQ[3][c];
        float* a8 = acc8 + ((blockIdx.x & 7) << 7);
        atomicAdd(&a8[c], s);
        atomicAdd(&a8[64 + c], q);
    }
}

// combine 8-copy accumulator -> BN scale/shift. Trivial (4 KB read).
__global__ __launch_bounds__(64) void bnpar_k(const float* __restrict__ acc8,
                                              const float* __restrict__ g,
                                              const float* __restrict__ b,
                                              float* __restrict__ st) {
    int c = threadIdx.x;
    float s = 0.f, q = 0.f;
#pragma unroll
    for (int i = 0; i < 8; ++i) {
        s += acc8[i * 128 + c];
        q += acc8[i * 128 + 64 + c];
    }
    float mu = s * (1.0f / NN);
    float var = q * (1.0f / NN) - mu * mu;
    float sc = g[c] * rsqrtf(var + EPS_BN);
    st[128 + c] = sc;
    st[192 + c] = b[c] - mu * sc;
}

// ============================================================================
// Vector node GEMM (tiny ro-projection head). BOUT stores ord16 keys.
// ============================================================================
template <int COUT, int CPW, int K, int IS, int OS, int MT, bool BNF, bool BOUT,
          bool POSF>
__global__ __launch_bounds__(256) void gemm_k(const float* __restrict__ in,
                                              const float* __restrict__ wT,
                                              const float* __restrict__ bias,
                                              const float* __restrict__ st,
                                              const float2* __restrict__ wp,
                                              const float2* __restrict__ pos2,
                                              float* __restrict__ out) {
    constexpr int CP = 4 * CPW;
    constexpr int RM = MT / 64;
    constexpr int XR = MT + 1;
    __shared__ __align__(16) float xs[K * XR];
    __shared__ __align__(16) float wsh[K * CP];
    int base = blockIdx.x * MT;
    for (int p = threadIdx.x; p < K * CP / 4; p += 256)
        ((float4*)wsh)[p] = ((const float4*)wT)[p];
    for (int p = threadIdx.x; p < MT * K; p += 256) {
        int n = p / K, j = p - n * K;
        float v = (base + n < NN) ? in[(size_t)(base + n) * IS + j] : 0.f;
        if constexpr (BNF) v = fmaxf(fmaf(v, st[128 + j], st[192 + j]), 0.f);
        xs[j * XR + n] = v;
    }
    __syncthreads();
    int wid = __builtin_amdgcn_readfirstlane(threadIdx.x >> 6);
    int lane = threadIdx.x & 63;
    int c0 = wid * CPW;
    if (c0 >= COUT) return;
    float acc[RM][CPW];
#pragma unroll
    for (int k = 0; k < CPW; ++k) {
        float bv = (c0 + k < COUT) ? bias[c0 + k] : 0.f;
#pragma unroll
        for (int r = 0; r < RM; ++r) acc[r][k] = bv;
    }
    for (int j = 0; j < K; ++j) {
        float a[RM];
#pragma unroll
        for (int r = 0; r < RM; ++r) a[r] = xs[j * XR + 64 * r + lane];
#pragma unroll
        for (int q = 0; q < CPW / 4; ++q) {
            float4 wv = *(const float4*)&wsh[j * CP + c0 + 4 * q];
#pragma unroll
            for (int r = 0; r < RM; ++r) {
                acc[r][4 * q + 0] = fmaf(a[r], wv.x, acc[r][4 * q + 0]);
                acc[r][4 * q + 1] = fmaf(a[r], wv.y, acc[r][4 * q + 1]);
                acc[r][4 * q + 2] = fmaf(a[r], wv.z, acc[r][4 * q + 2]);
                acc[r][4 * q + 3] = fmaf(a[r], wv.w, acc[r][4 * q + 3]);
            }
        }
    }
#pragma unroll
    for (int r = 0; r < RM; ++r) {
        int node = base + 64 * r + lane;
        if (node < NN) {
            float2 p = make_float2(0.f, 0.f);
            if constexpr (POSF) p = pos2[node];
#pragma unroll
            for (int k = 0; k < CPW; ++k) {
                if (c0 + k < COUT) {
                    float v = acc[r][k];
                    if constexpr (POSF) {
                        float2 w = wp[c0 + k];
                        v += p.x * w.x + p.y * w.y;
                    }
                    if constexpr (BOUT) {
                        unsigned short* ob = (unsigned short*)out;
                        ob[(size_t)node * OS + c0 + k] = ord16(f2b(v));
                    } else {
                        out[(size_t)node * OS + c0 + k] = v;
                    }
                }
            }
        }
    }
}

// ============================================================================
// MFMA final cls GEMM (flag-gated).
// ============================================================================
__global__ __launch_bounds__(256) void mfma_cls_k(
    const unsigned short* __restrict__ aggc16,
    const unsigned short* __restrict__ wcg16,
    const float* __restrict__ bgc,
    const int* __restrict__ flags,
    float* __restrict__ out) {
    if (flags[0] == 0) return;
    int wid = __builtin_amdgcn_readfirstlane(threadIdx.x >> 6);
    int lane = threadIdx.x & 63;
    int quad = lane >> 4;
    int l16 = lane & 15;
    int mbase = blockIdx.x * 64 + wid * 16;
    bf16x8 a[4];
    const unsigned short* arow = aggc16 + (size_t)(mbase + l16) * 128 + quad * 8;
#pragma unroll
    for (int kc = 0; kc < 4; ++kc)
        a[kc] = *(const bf16x8*)(arow + kc * 32);
    for (int t = 0; t < 7; ++t) {
        const unsigned short* brow = wcg16 + t * 2048 + l16 * 128 + quad * 8;
        f32x4 acc = {0.f, 0.f, 0.f, 0.f};
#pragma unroll
        for (int kc = 0; kc < 4; ++kc) {
            bf16x8 b = *(const bf16x8*)(brow + kc * 32);
            acc = __builtin_amdgcn_mfma_f32_16x16x32_bf16(a[kc], b, acc, 0, 0, 0);
        }
        int cg = t * 16 + l16;
        if (cg < NCLS) {
            float bv = bgc[cg];
#pragma unroll
            for (int r = 0; r < 4; ++r) {
                int rg = mbase + quad * 4 + r;
                if (rg < NN) out[(size_t)rg * NCLS + cg] = acc[r] + bv;
            }
        }
    }
}

// cls output = bias broadcast when wg_cls == 0.
__global__ __launch_bounds__(256) void fill_cls_k(const int* __restrict__ flags,
                                                  const float* __restrict__ bgc,
                                                  float* __restrict__ out) {
    if (flags[0] != 0) return;
    int idx = blockIdx.x * 256 + threadIdx.x;
    if (idx < NN * NCLS) out[idx] = bgc[idx % NCLS];
}

// ============================================================================
// Edge segment-max over CSR in the u16 KEY domain (wave per node, lane per
// dword). Aggregates written as bf16 (bit-identical downstream).
// ============================================================================
__global__ __launch_bounds__(256) void edge1_k(const unsigned short* __restrict__ y,  // u16 keys, stride 64
                                               const float2* __restrict__ pos2,
                                               const int* __restrict__ rs,
                                               const int* __restrict__ csrc,
                                               const float* __restrict__ wl,  // (64,66)
                                               unsigned* __restrict__ agg) {  // bf16 [n][64] as dwords
    int wid = __builtin_amdgcn_readfirstlane(threadIdx.x >> 6);
    int lane = threadIdx.x & 63;
    int node = blockIdx.x * 4 + wid;
    if (node >= NN) return;
    int l32 = lane & 31;
    int half = lane >> 5;
    int hoff = half << 2;
    const u16x2* yv = (const u16x2*)y;   // [NN][32]
    float2 pd = pos2[node];
    int i0 = rs[node], i1 = rs[node + 1];
    u16x2 acc0 = {KINIT, KINIT}, acc1 = {KINIT, KINIT};
    for (int ib = i0; ib < i1; ib += 64) {
        int m = i1 - ib;
        if (m > 64) m = 64;
        int t = ib + lane;
        int idx = (t < i1) ? csrc[t] : 0;
        int j = 0;
        for (; j + 8 <= m; j += 8) {
            u16x2 v[4];
#pragma unroll
            for (int p = 0; p < 4; ++p) {
                int row = bperm(((j + 2 * p) << 2) + hoff, idx);
                v[p] = yv[(size_t)row * 32 + l32];
            }
            acc0 = vmax2(acc0, v[0]);
            acc1 = vmax2(acc1, v[1]);
            acc0 = vmax2(acc0, v[2]);
            acc1 = vmax2(acc1, v[3]);
        }
        for (; j < m; j += 2) {
            int jj = j + half;
            if (jj > m - 1) jj = m - 1;
            int row = bperm(jj << 2, idx);
            acc0 = vmax2(acc0, yv[(size_t)row * 32 + l32]);
        }
    }
    u16x2 acc = vmax2(acc0, acc1);
    int accI = *(int*)&acc;
    int oth = __shfl_xor(accI, 32, 64);
    acc = vmax2(acc, *(u16x2*)&oth);
    if (lane < 32) {
        int c0 = l32 * 2;
        float w00 = wl[c0 * 66 + 64], w01 = wl[c0 * 66 + 65];
        float w10 = wl[c0 * 66 + 66 + 64], w11 = wl[c0 * 66 + 66 + 65];
        float v0 = fmaxf(iordf(acc.x) - fmaf(pd.y, w01, pd.x * w00), 0.f);
        float v1 = fmaxf(iordf(acc.y) - fmaf(pd.y, w11, pd.x * w10), 0.f);
        agg[(size_t)node * 32 + l32] =
            (unsigned)f2b(v0) | ((unsigned)f2b(v1) << 16);
    }
}

// y12: u16-key [n][64]{c1,c2} pairs -> one u16x2 per lane
__global__ __launch_bounds__(256) void edge2_k(const unsigned* __restrict__ y12,
                                               const float2* __restrict__ pos2,
                                               const int* __restrict__ rs,
                                               const int* __restrict__ csrc,
                                               const float* __restrict__ wlA,
                                               const float* __restrict__ wlB,
                                               unsigned short* __restrict__ a1,  // bf16 [n][64]
                                               unsigned short* __restrict__ a2) {
    int wid = __builtin_amdgcn_readfirstlane(threadIdx.x >> 6);
    int lane = threadIdx.x & 63;
    int node = blockIdx.x * 4 + wid;
    if (node >= NN) return;
    float wa0 = wlA[lane * 66 + 64], wa1 = wlA[lane * 66 + 65];
    float wb0 = wlB[lane * 66 + 64], wb1 = wlB[lane * 66 + 65];
    float2 pd = pos2[node];
    int i0 = rs[node], i1 = rs[node + 1];
    u16x2 acc0 = {KINIT, KINIT}, acc1 = {KINIT, KINIT};
    for (int ib = i0; ib < i1; ib += 64) {
        int m = i1 - ib;
        if (m > 64) m = 64;
        int t = ib + lane;
        int idx = (t < i1) ? csrc[t] : 0;
        int j = 0;
        for (; j + 8 <= m; j += 8) {
            u16x2 w[8];
#pragma unroll
            for (int q = 0; q < 8; ++q)
                w[q] = *(const u16x2*)(y12 + (size_t)rl_i(idx, j + q) * 64 + lane);
#pragma unroll
            for (int q = 0; q < 8; q += 2) {
                acc0 = vmax2(acc0, w[q]);
                acc1 = vmax2(acc1, w[q + 1]);
            }
        }
        for (; j < m; ++j)
            acc0 = vmax2(acc0,
                *(const u16x2*)(y12 + (size_t)rl_i(idx, j) * 64 + lane));
    }
    u16x2 acc = vmax2(acc0, acc1);
    a1[(size_t)node * 64 + lane] =
        f2b(fmaxf(iordf(acc.x) - fmaf(pd.y, wa1, pd.x * wa0), 0.0f));
    a2[(size_t)node * 64 + lane] =
        f2b(fmaxf(iordf(acc.y) - fmaf(pd.y, wb1, pd.x * wb0), 0.0f));
}

// cls edge pass (flag-gated), key domain, interleaved dword gathers.
__global__ __launch_bounds__(256) void edge_cls_k(
    const unsigned* __restrict__ y32,        // interleaved cls keys, stride 64
    const float2* __restrict__ pos2,
    const int* __restrict__ rs,
    const int* __restrict__ csrc,
    const float* __restrict__ wl,            // (101,66)
    const int* __restrict__ flags,
    unsigned short* __restrict__ aggb) {
    if (flags[0] == 0) return;
    int wid = __builtin_amdgcn_readfirstlane(threadIdx.x >> 6);
    int lane = threadIdx.x & 63;
    int node = blockIdx.x * 4 + wid;
    if (node >= NN) return;
    int chi = (lane + 64 < NCLS) ? (lane + 64) : (NCLS - 1);
    float wa0 = wl[lane * 66 + 64], wa1 = wl[lane * 66 + 65];
    float wb0 = wl[chi * 66 + 64], wb1 = wl[chi * 66 + 65];
    float2 pd = pos2[node];
    int i0 = rs[node], i1 = rs[node + 1];
    u16x2 acc0 = {KINIT, KINIT}, acc1 = {KINIT, KINIT};
    for (int ib = i0; ib < i1; ib += 64) {
        int m = i1 - ib;
        if (m > 64) m = 64;
        int t = ib + lane;
        int idx = (t < i1) ? csrc[t] : 0;
        int j = 0;
        for (; j + 8 <= m; j += 8) {
            u16x2 w[8];
#pragma unroll
            for (int q = 0; q < 8; ++q)
                w[q] = *(const u16x2*)(y32 + (size_t)rl_i(idx, j + q) * 64 + lane);
#pragma unroll
            for (int q = 0; q < 8; q += 2) {
                acc0 = vmax2(acc0, w[q]);
                acc1 = vmax2(acc1, w[q + 1]);
            }
        }
        for (; j < m; ++j)
            acc0 = vmax2(acc0,
                *(const u16x2*)(y32 + (size_t)rl_i(idx, j) * 64 + lane));
    }
    u16x2 acc = vmax2(acc0, acc1);
    aggb[(size_t)node * 128 + lane] =
        f2b(fmaxf(iordf(acc.x) - fmaf(pd.y, wa1, pd.x * wa0), 0.0f));
    unsigned short hb = (lane + 64 < NCLS)
        ? f2b(fmaxf(iordf(acc.y) - fmaf(pd.y, wb1, pd.x * wb0), 0.0f))
        : (unsigned short)0;
    aggb[(size_t)node * 128 + 64 + lane] = hb;
}

// reg/obj edge pass: wave per node; 8 edge-slots x 8 channel-slots.
__global__ __launch_bounds__(256) void edge_ro_k(
    const unsigned short* __restrict__ yro,  // keys, stride 8
    const float2* __restrict__ pos2,
    const int* __restrict__ rs,
    const int* __restrict__ csrc,
    const float2* __restrict__ wpro,         // [8]
    float* __restrict__ aggr,
    float* __restrict__ aggo) {
    int wid = __builtin_amdgcn_readfirstlane(threadIdx.x >> 6);
    int lane = threadIdx.x & 63;
    int node = blockIdx.x * 4 + wid;
    if (node >= NN) return;
    int k = lane >> 3, c = lane & 7;
    int cc = (c < 5) ? c : 4;
    float2 wv = wpro[cc];
    int i0 = rs[node], i1 = rs[node + 1];
    unsigned ka = KINIT;
    for (int i = i0 + k; i < i1; i += 8) {
        int s = csrc[i];
        unsigned kv = yro[(size_t)s * 8 + cc];
        ka = (kv > ka) ? kv : ka;
    }
    unsigned o;
    o = (unsigned)__shfl_xor((int)ka, 8, 64);  ka = (o > ka) ? o : ka;
    o = (unsigned)__shfl_xor((int)ka, 16, 64); ka = (o > ka) ? o : ka;
    o = (unsigned)__shfl_xor((int)ka, 32, 64); ka = (o > ka) ? o : ka;
    float2 pd = pos2[node];
    float acc_f = fmaxf(iordf(ka) - fmaf(pd.y, wv.y, pd.x * wv.x), 0.0f);
    if (lane < 5) {
        if (lane < 4) aggr[(size_t)node * 4 + lane] = acc_f;
        else          aggo[node] = acc_f;
    }
}

__global__ __launch_bounds__(256) void final_ro_k(const float* __restrict__ aggr,
                                                  const float* __restrict__ aggo,
                                                  const float* __restrict__ wgr,
                                                  const float* __restrict__ bgr,
                                                  const float* __restrict__ wgo,
                                                  const float* __restrict__ bgo,
                                                  float* __restrict__ out) {
    int n = blockIdx.x * 256 + threadIdx.x;
    if (n >= NN) return;
    float a0 = aggr[(size_t)n * 4 + 0], a1 = aggr[(size_t)n * 4 + 1];
    float a2 = aggr[(size_t)n * 4 + 2], a3 = aggr[(size_t)n * 4 + 3];
    float* reg = out + (size_t)NN * NCLS;
    float* obj = reg + (size_t)NN * 4;
#pragma unroll
    for (int k = 0; k < 4; ++k) {
        float acc = bgr[k];
        acc = fmaf(a0, wgr[k * 4 + 0], acc);
        acc = fmaf(a1, wgr[k * 4 + 1], acc);
        acc = fmaf(a2, wgr[k * 4 + 2], acc);
        acc = fmaf(a3, wgr[k * 4 + 3], acc);
        reg[(size_t)n * 4 + k] = acc;
    }
    obj[n] = fmaf(aggo[n], wgo[0], bgo[0]);
}

// ============================================================================
extern "C" void kernel_launch(void* const* d_in, const int* in_sizes, int n_in,
                              void* d_out, int out_size, void* d_ws, size_t ws_size,
                              hipStream_t stream) {
    const float* x   = (const float*)d_in[0];
    const float* pos = (const float*)d_in[1];
    const int* ei    = (const int*)d_in[2];
    const int* src = ei;
    const int* dst = ei + NE;
    const float* wl_stem = (const float*)d_in[3];
    const float* bl_stem = (const float*)d_in[4];
    const float* wg_stem = (const float*)d_in[5];
    const float* bg_stem = (const float*)d_in[6];
    const float* g_stem  = (const float*)d_in[7];
    const float* b_stem  = (const float*)d_in[8];
    const float* wl_c1 = (const float*)d_in[9];
    const float* bl_c1 = (const float*)d_in[10];
    const float* wg_c1 = (const float*)d_in[11];
    const float* bg_c1 = (const float*)d_in[12];
    const float* g_c1  = (const float*)d_in[13];
    const float* b_c1  = (const float*)d_in[14];
    const float* wl_c2 = (const float*)d_in[15];
    const float* bl_c2 = (const float*)d_in[16];
    const float* wg_c2 = (const float*)d_in[17];
    const float* bg_c2 = (const float*)d_in[18];
    const float* g_c2  = (const float*)d_in[19];
    const float* b_c2  = (const float*)d_in[20];
    const float* wl_reg = (const float*)d_in[21];
    const float* bl_reg = (const float*)d_in[22];
    const float* wg_reg = (const float*)d_in[23];
    const float* bg_reg = (const float*)d_in[24];
    const float* wl_cls = (const float*)d_in[25];
    const float* bl_cls = (const float*)d_in[26];
    const float* wg_cls = (const float*)d_in[27];
    const float* bg_cls = (const float*)d_in[28];
    const float* wl_obj = (const float*)d_in[29];
    const float* bl_obj = (const float*)d_in[30];
    const float* wg_obj = (const float*)d_in[31];
    const float* bg_obj = (const float*)d_in[32];

    float* ws = (float*)d_ws;
    // Arena: S0[N*128] | S1[N*64] | S2[N*64] | S3[N*64] | ints/smalls
    float* S0 = ws;
    float* S1 = S0 + (size_t)NN * 128;
    float* S2 = S1 + (size_t)NN * 64;
    float* S3 = S2 + (size_t)NN * 64;
    float* y12   = S0;       // key [n][128] (first half of S0)
    float* y_cls = S0;       // key [n][128] interleaved dwords
    // bf16 agg buffers in S0's second half (free during conv phases)
    unsigned short* B0 = (unsigned short*)(S0 + (size_t)NN * 64);  // [n][64] bf16
    unsigned short* B1 = B0 + (size_t)NN * 64;                     // [n][64] bf16
    unsigned short* aggc16 = (unsigned short*)S1;   // bf16 [n][128]
    int*   bstore = (int*)S0;                     // NBUCK*BCAP ints (CSR phase)
    int*   rs   = (int*)(S3 + (size_t)NN * 64);   // NN+1 (padded)
    int*   csrc = rs + 100016;                    // NE
    float* pos2 = (float*)(csrc + NE);            // NN float2
    float* y_ro = pos2 + (size_t)NN * 2;          // key [n][8] (fp32-sized slot)
    float* aggr = y_ro + (size_t)NN * 8;          // NN*4
    float* aggo = aggr + (size_t)NN * 4;          // NN
    float* st   = aggo + NN;                      // 3*256 (params at [128..255])
    float* st0 = st, *st1 = st + 256, *st2 = st + 512;
    float* wro = st + 768;                        // 336
    float* bro = wro + 336;                       // 16
    int*   bcnt16 = (int*)(bro + 16);             // NBUCK*16
    int*   flags  = bcnt16 + NBUCK * 16;          // 16 ints (zeroed with bcnt16)
    float* stacc  = (float*)(flags + 16);         // 3*1024 floats (zeroed too)
    float* stacc0 = stacc, *stacc1 = stacc + 1024, *stacc2 = stacc + 2048;
    int*   bbase  = (int*)(stacc + 3072);         // 256
    float* wT_ro = (float*)(bbase + 256);         // [64][16] fp32
    unsigned short* wb_sg = (unsigned short*)(wT_ro + 1024);  // 4096
    unsigned short* wb_g1 = wb_sg + 4096;                     // 4096
    unsigned short* wb_g2 = wb_g1 + 4096;                     // 4096
    unsigned short* wb_sp = wb_g2 + 4096;                     // 4096
    unsigned short* wb_12 = wb_sp + 4096;                     // 8192
    unsigned short* wb_cp = wb_12 + 8192;                     // 8192
    unsigned short* wcg16 = wb_cp + 8192;                     // 14336
    float* bAB   = (float*)(wcg16 + 14336);       // 128
    float* wp_sp = bAB + 128;                     // 128 (64 float2)
    float* wp_12 = wp_sp + 128;                   // 256 (128 float2)
    float* wp_cp = wp_12 + 256;                   // 256 (128 float2)
    float* wp_ro = wp_cp + 256;                   // 16  (8 float2)

    // zero bucket counters + flag + the 3 stat accumulators (contiguous)
    hipMemsetAsync(bcnt16, 0, (NBUCK * 16 + 16 + 3072) * sizeof(int), stream);

    const int NB = (NN + 255) / 256;      // 391
    const int N4 = (NN + 3) / 4;          // 25000
    const int CB = (NE + CHUNK - 1) / CHUNK;  // 782
    const int PB = (NN + 49157 + 255) / 256;  // pack_all grid (pos2 folded in)

    // ---- packing (+pos2+flag) + CSR build ----
    pack_all_k<<<PB, 256, 0, stream>>>(pos,
                                       wl_stem, wg_stem, wl_c1, bl_c1, wl_c2,
                                       bl_c2, wg_c1, wg_c2, wl_reg, wl_obj,
                                       bl_reg, bl_obj, wl_cls, wg_cls,
                                       (float2*)pos2, flags,
                                       wT_ro, wb_sg, wb_g1, wb_g2, wb_sp,
                                       wb_12, wb_cp, wcg16, bAB, wro, bro,
                                       wp_sp, wp_12, wp_cp, wp_ro);
    bucket_k<<<CB, 256, 0, stream>>>(src, dst, bcnt16, bstore);
    bscan_k<<<1, 256, 0, stream>>>(bcnt16, bbase);
    b2csr_k<<<NBUCK, 512, 0, stream>>>(bcnt16, bbase, bstore, rs, csrc);

    // ---- stem ----
    mfma_lin_k<64, 64, 64, 64, false, false, false><<<MBK, 256, 0, stream>>>(
        x, wb_sp, bl_stem, nullptr, (const float2*)wp_sp, (const float2*)pos2,
        flags, (unsigned short*)S1);   // z_stem keys
    edge1_k<<<N4, 256, 0, stream>>>((const unsigned short*)S1, (float2*)pos2, rs,
                                    csrc, wl_stem, (unsigned*)B0);  // bf16 agg
    mfma_stats_k<<<MBK, 256, 0, stream>>>(B0, wb_sg, bg_stem, S2, stacc0);
    bnpar_k<<<1, 64, 0, stream>>>(stacc0, g_stem, b_stem, st0);

    // ---- c1 + c2 (BN fused into packed MFMA projection, shared edge pass) ----
    mfma_lin_k<128, 128, 64, 128, true, false, false><<<MBK, 256, 0, stream>>>(
        S2, wb_12, bAB, st0, (const float2*)wp_12, (const float2*)pos2,
        flags, (unsigned short*)y12);  // z12 keys
    edge2_k<<<N4, 256, 0, stream>>>((const unsigned*)y12, (float2*)pos2, rs, csrc,
                                    wl_c1, wl_c2, B0, B1);  // bf16 aggs
    mfma_stats_k<<<MBK, 256, 0, stream>>>(B0, wb_g1, bg_c1, S1, stacc1);
    bnpar_k<<<1, 64, 0, stream>>>(stacc1, g_c1, b_c1, st1);
    mfma_stats_k<<<MBK, 256, 0, stream>>>(B1, wb_g2, bg_c2, S3, stacc2);
    bnpar_k<<<1, 64, 0, stream>>>(stacc2, g_c2, b_c2, st2);

    // ---- reg + obj projection (input x1 = BN(S1), fused; keys out) ----
    gemm_k<5, 4, 64, 64, 8, 192, true, true, true><<<G192B, 256, 0, stream>>>(
        S1, wT_ro, bro, st1, (const float2*)wp_ro, (const float2*)pos2, y_ro);
    // ---- cls projection (flag-gated; interleaved key pairs) ----
    mfma_lin_k<128, NCLS, 64, 128, true, true, true><<<MBK, 256, 0, stream>>>(
        S3, wb_cp, bl_cls, st2, (const float2*)wp_cp, (const float2*)pos2,
        flags, (unsigned short*)y_cls);

    // ---- cls edge pass (flag-gated) + reg/obj edge pass ----
    edge_cls_k<<<N4, 256, 0, stream>>>((const unsigned*)y_cls, (float2*)pos2,
                                       rs, csrc, wl_cls, flags, aggc16);
    edge_ro_k<<<N4, 256, 0, stream>>>((const unsigned short*)y_ro,
                                      (float2*)pos2, rs, csrc,
                                      (const float2*)wp_ro, aggr, aggo);

    mfma_cls_k<<<MBK, 256, 0, stream>>>(aggc16, wcg16, bg_cls, flags,
                                        (float*)d_out);
    fill_cls_k<<<(NN * NCLS + 255) / 256, 256, 0, stream>>>(flags, bg_cls,
                                                            (float*)d_out);
    final_ro_k<<<NB, 256, 0, stream>>>(aggr, aggo, wg_reg, bg_reg, wg_obj, bg_obj,
                                       (float*)d_out);
}